// Round 1
// baseline (138.059 us; speedup 1.0000x reference)
//
#include <hip/hip_runtime.h>

#define NB 16     // batch
#define CD 128    // channels
#define HW 4096   // spatial L
#define DD 512    // projected dim
#define KC 64     // clusters

typedef __attribute__((ext_vector_type(8))) short bfrag;           // 8 bf16 (4 VGPR)
typedef __attribute__((ext_vector_type(4))) float facc;            // MFMA acc
typedef __attribute__((ext_vector_type(4))) unsigned short upk4;   // 4 bf16 pack

__device__ __forceinline__ unsigned short f2bf(float f) {
  union { float f; unsigned u; } v; v.f = f;
  unsigned r = v.u + 0x7fffu + ((v.u >> 16) & 1u);   // RNE
  return (unsigned short)(r >> 16);
}

// ---------- prep: centroid L2-normalize -> bf16 ; conv_w -> bf16 ----------
__global__ __launch_bounds__(256) void k_prep(const float* __restrict__ conv_w,
                                              const float* __restrict__ centroids,
                                              unsigned short* __restrict__ Wb,
                                              unsigned short* __restrict__ Cb) {
  int b = blockIdx.x, t = threadIdx.x;
  if (b < KC) {
    const float* row = centroids + (size_t)b * DD;
    float v0 = row[t], v1 = row[t + 256];
    float ss = v0 * v0 + v1 * v1;
    #pragma unroll
    for (int off = 32; off; off >>= 1) ss += __shfl_xor(ss, off);
    __shared__ float red[4];
    if ((t & 63) == 0) red[t >> 6] = ss;
    __syncthreads();
    float tot = red[0] + red[1] + red[2] + red[3];
    float inv = 1.0f / fmaxf(sqrtf(tot), 1e-12f);
    Cb[(size_t)b * DD + t]       = f2bf(v0 * inv);
    Cb[(size_t)b * DD + t + 256] = f2bf(v1 * inv);
  } else {
    int i = (b - KC) * 2048 + t * 8;            // 32 blocks cover 65536 elems
    const float4* src = (const float4*)(conv_w + i);
    float4 a = src[0], c = src[1];
    upk4 w0, w1;
    w0[0] = f2bf(a.x); w0[1] = f2bf(a.y); w0[2] = f2bf(a.z); w0[3] = f2bf(a.w);
    w1[0] = f2bf(c.x); w1[1] = f2bf(c.y); w1[2] = f2bf(c.z); w1[3] = f2bf(c.w);
    *(upk4*)(Wb + i)     = w0;
    *(upk4*)(Wb + i + 4) = w1;
  }
}

// ---------- x: (N,C,L) fp32 -> Xnt: (N,L,C) bf16, L2-normalized over C ----------
__global__ __launch_bounds__(256) void k_xnorm(const float* __restrict__ x,
                                               unsigned short* __restrict__ Xnt) {
  __shared__ float tile[32][CD + 1];
  __shared__ float invn[32];
  int n = blockIdx.x >> 7;
  int l0 = (blockIdx.x & 127) * 32;
  int t = threadIdx.x;
  int li = t & 31, c0 = t >> 5;
  const float* xb = x + (size_t)n * CD * HW + l0;
  #pragma unroll
  for (int c = c0; c < CD; c += 8)
    tile[li][c] = xb[(size_t)c * HW + li];
  __syncthreads();
  int l = t >> 3, j = t & 7;
  float ss = 0.f;
  #pragma unroll
  for (int c = j; c < CD; c += 8) { float v = tile[l][c]; ss += v * v; }
  ss += __shfl_xor(ss, 1); ss += __shfl_xor(ss, 2); ss += __shfl_xor(ss, 4);
  if (j == 0) invn[l] = 1.0f / fmaxf(sqrtf(ss), 1e-12f);
  __syncthreads();
  int c = t & 127, lr = t >> 7;
  #pragma unroll
  for (int l2 = lr; l2 < 32; l2 += 2)
    Xnt[((size_t)n * HW + l0 + l2) * CD + c] = f2bf(tile[l2][c] * invn[l2]);
}

// ---------- generic BT-form bf16 MFMA GEMM ----------
// C[M,N] = A[M,K] * B[N,K]^T ; both operands K-contiguous bf16; fp32 accum.
// EPI: 0 = bf16 out + bias[gcol]; 1 = bf16 out + bias[grow]; 2 = f32 out; 3 = f32 split-K partials
template<int BM, int BN, int BK, int KLEN, int LDA, int LDB, int LDC,
         int SA, int SB, int SC, int NTM, int NTN, int EPI>
__global__ __launch_bounds__(256) void gemm_bt(const unsigned short* __restrict__ A,
                                               const unsigned short* __restrict__ B,
                                               void* __restrict__ Cout,
                                               const float* __restrict__ bias) {
  constexpr int WM = BM / 2, WN = BN / 2;
  constexpr int FM = WM / 16, FN = WN / 16;
  constexpr int CH = BK / 8;
  __shared__ unsigned short As[BM][BK + 8];
  __shared__ unsigned short Bs[BN][BK + 8];
  int t = threadIdx.x, lane = t & 63, wid = t >> 6;
  int wr = wid >> 1, wc = wid & 1;
  int bx = blockIdx.x;
  int tn = bx % NTN; bx /= NTN;
  int tm = bx % NTM; int sk = bx / NTM;
  int n = blockIdx.y;
  const unsigned short* Ab = A + (size_t)n * SA + (size_t)tm * BM * LDA + (size_t)sk * KLEN;
  const unsigned short* Bb = B + (size_t)n * SB + (size_t)tn * BN * LDB + (size_t)sk * KLEN;
  facc acc[FM][FN];
  facc zero = {0.f, 0.f, 0.f, 0.f};
  #pragma unroll
  for (int m = 0; m < FM; m++)
    #pragma unroll
    for (int j = 0; j < FN; j++) acc[m][j] = zero;

  for (int kt = 0; kt < KLEN; kt += BK) {
    #pragma unroll
    for (int i = t; i < BM * CH; i += 256) {
      int r = i / CH, cc = (i % CH) * 8;
      *(bfrag*)&As[r][cc] = *(const bfrag*)&Ab[(size_t)r * LDA + kt + cc];
    }
    #pragma unroll
    for (int i = t; i < BN * CH; i += 256) {
      int r = i / CH, cc = (i % CH) * 8;
      *(bfrag*)&Bs[r][cc] = *(const bfrag*)&Bb[(size_t)r * LDB + kt + cc];
    }
    __syncthreads();
    #pragma unroll
    for (int kk = 0; kk < BK; kk += 32) {
      int krow = kk + ((lane >> 4) << 3);
      bfrag af[FM], bf[FN];
      #pragma unroll
      for (int m = 0; m < FM; m++)
        af[m] = *(const bfrag*)&As[wr * WM + m * 16 + (lane & 15)][krow];
      #pragma unroll
      for (int j = 0; j < FN; j++)
        bf[j] = *(const bfrag*)&Bs[wc * WN + j * 16 + (lane & 15)][krow];
      #pragma unroll
      for (int m = 0; m < FM; m++)
        #pragma unroll
        for (int j = 0; j < FN; j++)
          acc[m][j] = __builtin_amdgcn_mfma_f32_16x16x32_bf16(af[m], bf[j], acc[m][j], 0, 0, 0);
    }
    __syncthreads();
  }

  int r0 = (lane >> 4) << 2, cl = lane & 15;
  size_t cb = (EPI == 3) ? ((size_t)(sk * NB + n)) * SC : (size_t)n * SC;
  #pragma unroll
  for (int m = 0; m < FM; m++) {
    int grow = tm * BM + wr * WM + m * 16 + r0;
    #pragma unroll
    for (int j = 0; j < FN; j++) {
      int gcol = tn * BN + wc * WN + j * 16 + cl;
      if constexpr (EPI == 0) {
        unsigned short* o = (unsigned short*)Cout;
        float bv = bias[gcol];
        #pragma unroll
        for (int q = 0; q < 4; q++)
          o[cb + (size_t)(grow + q) * LDC + gcol] = f2bf(acc[m][j][q] + bv);
      } else if constexpr (EPI == 1) {
        unsigned short* o = (unsigned short*)Cout;
        float bq[4];
        *(float4*)bq = *(const float4*)(bias + grow);
        #pragma unroll
        for (int q = 0; q < 4; q++)
          o[cb + (size_t)(grow + q) * LDC + gcol] = f2bf(acc[m][j][q] + bq[q]);
      } else {
        float* o = (float*)Cout;
        #pragma unroll
        for (int q = 0; q < 4; q++)
          o[cb + (size_t)(grow + q) * LDC + gcol] = acc[m][j][q];
      }
    }
  }
}

// ---------- softmax over L=4096 per (n,k) row; fp32 in, bf16 out ----------
__global__ __launch_bounds__(256) void k_softmax(const float* __restrict__ logits,
                                                 unsigned short* __restrict__ s) {
  int row = blockIdx.x;
  const float4* in = (const float4*)(logits + (size_t)row * HW);
  int t = threadIdx.x, wid = t >> 6;
  float4 v[4];
  float mx = -3.4e38f;
  #pragma unroll
  for (int j = 0; j < 4; j++) {
    v[j] = in[j * 256 + t];
    mx = fmaxf(mx, fmaxf(fmaxf(v[j].x, v[j].y), fmaxf(v[j].z, v[j].w)));
  }
  #pragma unroll
  for (int off = 32; off; off >>= 1) mx = fmaxf(mx, __shfl_xor(mx, off));
  __shared__ float redm[4], reds[4];
  if ((t & 63) == 0) redm[wid] = mx;
  __syncthreads();
  mx = fmaxf(fmaxf(redm[0], redm[1]), fmaxf(redm[2], redm[3]));
  float e[4][4];
  float sum = 0.f;
  #pragma unroll
  for (int j = 0; j < 4; j++) {
    e[j][0] = __expf(v[j].x - mx); e[j][1] = __expf(v[j].y - mx);
    e[j][2] = __expf(v[j].z - mx); e[j][3] = __expf(v[j].w - mx);
    sum += e[j][0] + e[j][1] + e[j][2] + e[j][3];
  }
  #pragma unroll
  for (int off = 32; off; off >>= 1) sum += __shfl_xor(sum, off);
  if ((t & 63) == 0) reds[wid] = sum;
  __syncthreads();
  sum = reds[0] + reds[1] + reds[2] + reds[3];
  float rinv = 1.0f / sum;
  upk4* o = (upk4*)(s + (size_t)row * HW);
  #pragma unroll
  for (int j = 0; j < 4; j++) {
    upk4 w;
    w[0] = f2bf(e[j][0] * rinv); w[1] = f2bf(e[j][1] * rinv);
    w[2] = f2bf(e[j][2] * rinv); w[3] = f2bf(e[j][3] * rinv);
    o[j * 256 + t] = w;
  }
}

// ---------- reduce split-K partials ----------
__global__ __launch_bounds__(256) void k_reduce(const float* __restrict__ part,
                                                float* __restrict__ out) {
  int i = blockIdx.x * 256 + threadIdx.x;
  float s = 0.f;
  #pragma unroll
  for (int skk = 0; skk < 8; skk++) s += part[(size_t)skk * (NB * KC * DD) + i];
  out[i] = s;
}

extern "C" void kernel_launch(void* const* d_in, const int* in_sizes, int n_in,
                              void* d_out, int out_size, void* d_ws, size_t ws_size,
                              hipStream_t stream) {
  const float* x         = (const float*)d_in[0];
  const float* conv_w    = (const float*)d_in[1];
  const float* conv_b    = (const float*)d_in[2];
  const float* centroids = (const float*)d_in[3];
  float* out = (float*)d_out;
  char* ws = (char*)d_ws;

  // ws layout (bytes) — total 167,968,768:
  //   Wb   @ 0          (128 KB)   conv_w bf16 (D,C)
  //   Cb   @ 131072     (64 KB)    normalized centroids bf16 (K,D)
  //   Xnt  @ 196608     (16 MB)    normalized x bf16 (N,L,C)   [s aliases after g1b]
  //   fT   @ 16973824   (64 MB)    f bf16 (N,L,D)
  //   fdl  @ 84082688   (64 MB)    f bf16 (N,D,L)
  //   log  @ 151191552  (16 MB)    logits fp32 (N,K,L)         [partials alias after softmax]
  unsigned short* Wb  = (unsigned short*)(ws);
  unsigned short* Cb  = (unsigned short*)(ws + 131072);
  unsigned short* Xnt = (unsigned short*)(ws + 196608);
  unsigned short* fT  = (unsigned short*)(ws + 16973824ull);
  unsigned short* fdl = (unsigned short*)(ws + 84082688ull);
  float*          lg  = (float*)(ws + 151191552ull);
  unsigned short* sm  = (unsigned short*)(ws + 196608);        // alias Xnt (dead)
  float*          part= (float*)(ws + 151191552ull);            // alias logits (dead)

  k_prep<<<dim3(96), dim3(256), 0, stream>>>(conv_w, centroids, Wb, Cb);
  k_xnorm<<<dim3(2048), dim3(256), 0, stream>>>(x, Xnt);

  // fT(L,D) = Xnt(L,C) * Wb(D,C)^T + b[d]
  gemm_bt<128, 128, 64, 128, CD, CD, DD, CD * HW, 0, HW * DD, 32, 4, 0>
      <<<dim3(128, NB), dim3(256), 0, stream>>>(Xnt, Wb, (void*)fT, conv_b);
  // fdl(D,L) = Wb(D,C) * Xnt(L,C)^T + b[d]
  gemm_bt<128, 128, 64, 128, CD, CD, HW, 0, CD * HW, DD * HW, 4, 32, 1>
      <<<dim3(128, NB), dim3(256), 0, stream>>>(Wb, Xnt, (void*)fdl, conv_b);
  // logits(K,L) = Cb(K,D) * fT(L,D)^T
  gemm_bt<64, 128, 64, 512, DD, DD, HW, 0, HW * DD, KC * HW, 1, 32, 2>
      <<<dim3(32, NB), dim3(256), 0, stream>>>(Cb, fT, (void*)lg, nullptr);

  k_softmax<<<dim3(NB * KC), dim3(256), 0, stream>>>(lg, sm);

  // vlad partials: s(K,L) * fdl(D,L)^T, split-K over L into 8 chunks of 512
  gemm_bt<64, 128, 64, 512, HW, HW, DD, KC * HW, DD * HW, KC * DD, 1, 4, 3>
      <<<dim3(32, NB), dim3(256), 0, stream>>>(sm, fdl, (void*)part, nullptr);

  k_reduce<<<dim3(NB * KC * DD / 256), dim3(256), 0, stream>>>(part, out);

  (void)in_sizes; (void)n_in; (void)out_size; (void)ws_size;
}

// Round 2
// 110.011 us; speedup vs baseline: 1.2550x; 1.2550x over previous
//
#include <hip/hip_runtime.h>

#define NB 16     // batch
#define CD 128    // channels
#define HW 4096   // spatial L
#define DD 512    // projected dim
#define KC 64     // clusters

typedef __attribute__((ext_vector_type(8))) short bfrag;           // 8 bf16 (4 VGPR)
typedef __attribute__((ext_vector_type(4))) float facc;            // MFMA acc
typedef __attribute__((ext_vector_type(4))) unsigned short upk4;   // 4 bf16 pack

__device__ __forceinline__ unsigned short f2bf(float f) {
  union { float f; unsigned u; } v; v.f = f;
  unsigned r = v.u + 0x7fffu + ((v.u >> 16) & 1u);   // RNE
  return (unsigned short)(r >> 16);
}

// async global->LDS, 16B per lane. LDS dest = wave-uniform base + lane*16 (HW rule).
__device__ __forceinline__ void gll16(const void* g, void* l) {
  __builtin_amdgcn_global_load_lds(
      (__attribute__((address_space(1))) void*)(uintptr_t)g,
      (__attribute__((address_space(3))) void*)(uintptr_t)l, 16, 0, 0);
}

// ---------- prep: centroid L2-normalize -> bf16 ; conv_w -> bf16 ----------
__global__ __launch_bounds__(256) void k_prep(const float* __restrict__ conv_w,
                                              const float* __restrict__ centroids,
                                              unsigned short* __restrict__ Wb,
                                              unsigned short* __restrict__ Cb) {
  int b = blockIdx.x, t = threadIdx.x;
  if (b < KC) {
    const float* row = centroids + (size_t)b * DD;
    float v0 = row[t], v1 = row[t + 256];
    float ss = v0 * v0 + v1 * v1;
    #pragma unroll
    for (int off = 32; off; off >>= 1) ss += __shfl_xor(ss, off);
    __shared__ float red[4];
    if ((t & 63) == 0) red[t >> 6] = ss;
    __syncthreads();
    float tot = red[0] + red[1] + red[2] + red[3];
    float inv = 1.0f / fmaxf(sqrtf(tot), 1e-12f);
    Cb[(size_t)b * DD + t]       = f2bf(v0 * inv);
    Cb[(size_t)b * DD + t + 256] = f2bf(v1 * inv);
  } else {
    int i = (b - KC) * 2048 + t * 8;            // 32 blocks cover 65536 elems
    const float4* src = (const float4*)(conv_w + i);
    float4 a = src[0], c = src[1];
    upk4 w0, w1;
    w0[0] = f2bf(a.x); w0[1] = f2bf(a.y); w0[2] = f2bf(a.z); w0[3] = f2bf(a.w);
    w1[0] = f2bf(c.x); w1[1] = f2bf(c.y); w1[2] = f2bf(c.z); w1[3] = f2bf(c.w);
    *(upk4*)(Wb + i)     = w0;
    *(upk4*)(Wb + i + 4) = w1;
  }
}

// ---------- x: (N,C,L) fp32 -> Xnt: (N,L,C) bf16, L2-normalized over C ----------
__global__ __launch_bounds__(256) void k_xnorm(const float* __restrict__ x,
                                               unsigned short* __restrict__ Xnt) {
  __shared__ float tile[32][CD + 1];
  __shared__ float invn[32];
  int n = blockIdx.x >> 7;
  int l0 = (blockIdx.x & 127) * 32;
  int t = threadIdx.x;
  int li = t & 31, c0 = t >> 5;
  const float* xb = x + (size_t)n * CD * HW + l0;
  #pragma unroll
  for (int c = c0; c < CD; c += 8)
    tile[li][c] = xb[(size_t)c * HW + li];
  __syncthreads();
  int l = t >> 3, j = t & 7;
  float ss = 0.f;
  #pragma unroll
  for (int c = j; c < CD; c += 8) { float v = tile[l][c]; ss += v * v; }
  ss += __shfl_xor(ss, 1); ss += __shfl_xor(ss, 2); ss += __shfl_xor(ss, 4);
  if (j == 0) invn[l] = 1.0f / fmaxf(sqrtf(ss), 1e-12f);
  __syncthreads();
  int c = t & 127, lr = t >> 7;
  #pragma unroll
  for (int l2 = lr; l2 < 32; l2 += 2)
    Xnt[((size_t)n * HW + l0 + l2) * CD + c] = f2bf(tile[l2][c] * invn[l2]);
}

// ---------- generic BT-form bf16 MFMA GEMM, global_load_lds staging ----------
// C[M,N] = A[M,K] * B[N,K]^T ; both operands K-contiguous bf16; fp32 accum.
// EPI: 0 = dual bf16 out (Cout row-major + Cout2 transposed) with bias[gcol]
//      2 = f32 out; 3 = f32 split-K partials
template<int BM, int BN, int BK, int KLEN, int LDA, int LDB, int LDC, int LDC2,
         int SA, int SB, int SC, int SC2, int NTM, int NTN, int EPI>
__global__ __launch_bounds__(256) void gemm_bt(const unsigned short* __restrict__ A,
                                               const unsigned short* __restrict__ B,
                                               void* __restrict__ Cout,
                                               void* __restrict__ Cout2,
                                               const float* __restrict__ bias) {
  constexpr int WM = BM / 2, WN = BN / 2;
  constexpr int FM = WM / 16, FN = WN / 16;
  constexpr int ISS_A = (BM * BK) / 2048;   // grand issues: 256 lanes x 16B
  constexpr int ISS_B = (BN * BK) / 2048;
  __shared__ __align__(16) unsigned short As[BM][BK];   // linear: gload_lds needs it
  __shared__ __align__(16) unsigned short Bs[BN][BK];
  int t = threadIdx.x, lane = t & 63, wid = t >> 6;
  int wr = wid >> 1, wc = wid & 1;
  int bx = blockIdx.x;
  int tn = bx % NTN; bx /= NTN;
  int tm = bx % NTM; int sk = bx / NTM;
  int n = blockIdx.y;
  const unsigned short* Ab = A + (size_t)n * SA + (size_t)tm * BM * LDA + (size_t)sk * KLEN;
  const unsigned short* Bb = B + (size_t)n * SB + (size_t)tn * BN * LDB + (size_t)sk * KLEN;
  facc acc[FM][FN];
  facc zero = {0.f, 0.f, 0.f, 0.f};
  #pragma unroll
  for (int m = 0; m < FM; m++)
    #pragma unroll
    for (int j = 0; j < FN; j++) acc[m][j] = zero;

  for (int kt = 0; kt < KLEN; kt += BK) {
    #pragma unroll
    for (int q = 0; q < ISS_A; q++) {
      int chunk = (q * 4 + wid) * 64 + lane;          // 16B chunk id, row-major [BM][BK]
      int r = chunk >> 3, c8 = (chunk & 7) << 3;
      gll16(Ab + (size_t)r * LDA + kt + c8, (char*)As + (q * 4 + wid) * 1024);
    }
    #pragma unroll
    for (int q = 0; q < ISS_B; q++) {
      int chunk = (q * 4 + wid) * 64 + lane;
      int r = chunk >> 3, c8 = (chunk & 7) << 3;
      gll16(Bb + (size_t)r * LDB + kt + c8, (char*)Bs + (q * 4 + wid) * 1024);
    }
    __syncthreads();                                  // drains vmcnt -> LDS valid
    #pragma unroll
    for (int kk = 0; kk < BK; kk += 32) {
      int krow = kk + ((lane >> 4) << 3);
      bfrag af[FM], bf[FN];
      #pragma unroll
      for (int m = 0; m < FM; m++)
        af[m] = *(const bfrag*)&As[wr * WM + m * 16 + (lane & 15)][krow];
      #pragma unroll
      for (int j = 0; j < FN; j++)
        bf[j] = *(const bfrag*)&Bs[wc * WN + j * 16 + (lane & 15)][krow];
      #pragma unroll
      for (int m = 0; m < FM; m++)
        #pragma unroll
        for (int j = 0; j < FN; j++)
          acc[m][j] = __builtin_amdgcn_mfma_f32_16x16x32_bf16(af[m], bf[j], acc[m][j], 0, 0, 0);
    }
    __syncthreads();
  }

  int r0 = (lane >> 4) << 2, cl = lane & 15;
  size_t cb = (EPI == 3) ? ((size_t)(sk * NB + n)) * SC : (size_t)n * SC;
  #pragma unroll
  for (int m = 0; m < FM; m++) {
    int grow = tm * BM + wr * WM + m * 16 + r0;
    #pragma unroll
    for (int j = 0; j < FN; j++) {
      int gcol = tn * BN + wc * WN + j * 16 + cl;
      if constexpr (EPI == 0) {
        unsigned short* o  = (unsigned short*)Cout;   // (M,N) row-major
        unsigned short* o2 = (unsigned short*)Cout2;  // (N,M) transposed
        float bv = bias[gcol];
        upk4 tw;
        #pragma unroll
        for (int q = 0; q < 4; q++) {
          unsigned short h = f2bf(acc[m][j][q] + bv);
          o[cb + (size_t)(grow + q) * LDC + gcol] = h;
          tw[q] = h;
        }
        *(upk4*)&o2[(size_t)n * SC2 + (size_t)gcol * LDC2 + grow] = tw;
      } else {
        float* o = (float*)Cout;
        #pragma unroll
        for (int q = 0; q < 4; q++)
          o[cb + (size_t)(grow + q) * LDC + gcol] = acc[m][j][q];
      }
    }
  }
}

// ---------- softmax over L=4096 per (n,k) row; fp32 in, bf16 out ----------
__global__ __launch_bounds__(256) void k_softmax(const float* __restrict__ logits,
                                                 unsigned short* __restrict__ s) {
  int row = blockIdx.x;
  const float4* in = (const float4*)(logits + (size_t)row * HW);
  int t = threadIdx.x, wid = t >> 6;
  float4 v[4];
  float mx = -3.4e38f;
  #pragma unroll
  for (int j = 0; j < 4; j++) {
    v[j] = in[j * 256 + t];
    mx = fmaxf(mx, fmaxf(fmaxf(v[j].x, v[j].y), fmaxf(v[j].z, v[j].w)));
  }
  #pragma unroll
  for (int off = 32; off; off >>= 1) mx = fmaxf(mx, __shfl_xor(mx, off));
  __shared__ float redm[4], reds[4];
  if ((t & 63) == 0) redm[wid] = mx;
  __syncthreads();
  mx = fmaxf(fmaxf(redm[0], redm[1]), fmaxf(redm[2], redm[3]));
  float e[4][4];
  float sum = 0.f;
  #pragma unroll
  for (int j = 0; j < 4; j++) {
    e[j][0] = __expf(v[j].x - mx); e[j][1] = __expf(v[j].y - mx);
    e[j][2] = __expf(v[j].z - mx); e[j][3] = __expf(v[j].w - mx);
    sum += e[j][0] + e[j][1] + e[j][2] + e[j][3];
  }
  #pragma unroll
  for (int off = 32; off; off >>= 1) sum += __shfl_xor(sum, off);
  if ((t & 63) == 0) reds[wid] = sum;
  __syncthreads();
  sum = reds[0] + reds[1] + reds[2] + reds[3];
  float rinv = 1.0f / sum;
  upk4* o = (upk4*)(s + (size_t)row * HW);
  #pragma unroll
  for (int j = 0; j < 4; j++) {
    upk4 w;
    w[0] = f2bf(e[j][0] * rinv); w[1] = f2bf(e[j][1] * rinv);
    w[2] = f2bf(e[j][2] * rinv); w[3] = f2bf(e[j][3] * rinv);
    o[j * 256 + t] = w;
  }
}

// ---------- reduce split-K partials ----------
__global__ __launch_bounds__(256) void k_reduce(const float* __restrict__ part,
                                                float* __restrict__ out) {
  int i = blockIdx.x * 256 + threadIdx.x;
  float s = 0.f;
  #pragma unroll
  for (int skk = 0; skk < 8; skk++) s += part[(size_t)skk * (NB * KC * DD) + i];
  out[i] = s;
}

extern "C" void kernel_launch(void* const* d_in, const int* in_sizes, int n_in,
                              void* d_out, int out_size, void* d_ws, size_t ws_size,
                              hipStream_t stream) {
  const float* x         = (const float*)d_in[0];
  const float* conv_w    = (const float*)d_in[1];
  const float* conv_b    = (const float*)d_in[2];
  const float* centroids = (const float*)d_in[3];
  float* out = (float*)d_out;
  char* ws = (char*)d_ws;

  // ws layout (bytes):
  //   Wb   @ 0          (128 KB)   conv_w bf16 (D,C)
  //   Cb   @ 131072     (64 KB)    normalized centroids bf16 (K,D)
  //   Xnt  @ 196608     (16 MB)    normalized x bf16 (N,L,C)   [sm aliases after proj]
  //   fT   @ 16973824   (64 MB)    f bf16 (N,L,D)
  //   fdl  @ 84082688   (64 MB)    f bf16 (N,D,L)  — written by proj epilogue
  //   lg   @ 151191552  (16 MB)    logits fp32 (N,K,L)         [partials alias after softmax]
  unsigned short* Wb  = (unsigned short*)(ws);
  unsigned short* Cb  = (unsigned short*)(ws + 131072);
  unsigned short* Xnt = (unsigned short*)(ws + 196608);
  unsigned short* fT  = (unsigned short*)(ws + 16973824ull);
  unsigned short* fdl = (unsigned short*)(ws + 84082688ull);
  float*          lg  = (float*)(ws + 151191552ull);
  unsigned short* sm  = (unsigned short*)(ws + 196608);        // alias Xnt (dead)
  float*          part= (float*)(ws + 151191552ull);           // alias lg (dead)

  k_prep<<<dim3(96), dim3(256), 0, stream>>>(conv_w, centroids, Wb, Cb);
  k_xnorm<<<dim3(2048), dim3(256), 0, stream>>>(x, Xnt);

  // proj: fT(L,D) = Xnt(L,C) * Wb(D,C)^T + b[d]; dual-writes fdl(D,L) from epilogue
  gemm_bt<128, 128, 64, 128, CD, CD, DD, HW, CD * HW, 0, HW * DD, DD * HW, 32, 4, 0>
      <<<dim3(128, NB), dim3(256), 0, stream>>>(Xnt, Wb, (void*)fT, (void*)fdl, conv_b);
  // logits(K,L) = Cb(K,D) * fT(L,D)^T
  gemm_bt<64, 128, 64, 512, DD, DD, HW, 0, 0, HW * DD, KC * HW, 0, 1, 32, 2>
      <<<dim3(32, NB), dim3(256), 0, stream>>>(Cb, fT, (void*)lg, nullptr, nullptr);

  k_softmax<<<dim3(NB * KC), dim3(256), 0, stream>>>(lg, sm);

  // vlad partials: s(K,L) * fdl(D,L)^T, split-K over L into 8 chunks of 512
  gemm_bt<64, 128, 64, 512, HW, HW, DD, 0, KC * HW, DD * HW, KC * DD, 0, 1, 4, 3>
      <<<dim3(32, NB), dim3(256), 0, stream>>>(sm, fdl, (void*)part, nullptr, nullptr);

  k_reduce<<<dim3(NB * KC * DD / 256), dim3(256), 0, stream>>>(part, out);

  (void)in_sizes; (void)n_in; (void)out_size; (void)ws_size;
}

// Round 3
// 79.418 us; speedup vs baseline: 1.7384x; 1.3852x over previous
//
#include <hip/hip_runtime.h>

#define NB 16     // batch
#define CD 128    // channels
#define HW 4096   // spatial L
#define DD 512    // projected dim
#define KC 64     // clusters

typedef __attribute__((ext_vector_type(8))) short bfrag;           // 8 bf16 (4 VGPR)
typedef __attribute__((ext_vector_type(8))) unsigned short upk8;   // 8 bf16
typedef __attribute__((ext_vector_type(4))) float facc;            // MFMA acc
typedef __attribute__((ext_vector_type(4))) unsigned short upk4;   // 4 bf16

__device__ __forceinline__ unsigned short f2bf(float f) {
  union { float f; unsigned u; } v; v.f = f;
  unsigned r = v.u + 0x7fffu + ((v.u >> 16) & 1u);   // RNE
  return (unsigned short)(r >> 16);
}
__device__ __forceinline__ float bf2f(unsigned short h) {
  union { unsigned u; float f; } v; v.u = ((unsigned)h) << 16; return v.f;
}

// async global->LDS, 16B per lane (used by logits GEMM staging)
__device__ __forceinline__ void gll16(const void* g, void* l) {
  __builtin_amdgcn_global_load_lds(
      (__attribute__((address_space(1))) void*)(uintptr_t)g,
      (__attribute__((address_space(3))) void*)(uintptr_t)l, 16, 0, 0);
}

// ---------- prep: centroid L2-normalize -> bf16 ; conv_w -> bf16 ----------
__global__ __launch_bounds__(256) void k_prep(const float* __restrict__ conv_w,
                                              const float* __restrict__ centroids,
                                              unsigned short* __restrict__ Wb,
                                              unsigned short* __restrict__ Cb) {
  int b = blockIdx.x, t = threadIdx.x;
  if (b < KC) {
    const float* row = centroids + (size_t)b * DD;
    float v0 = row[t], v1 = row[t + 256];
    float ss = v0 * v0 + v1 * v1;
    #pragma unroll
    for (int off = 32; off; off >>= 1) ss += __shfl_xor(ss, off);
    __shared__ float red[4];
    if ((t & 63) == 0) red[t >> 6] = ss;
    __syncthreads();
    float tot = red[0] + red[1] + red[2] + red[3];
    float inv = 1.0f / fmaxf(sqrtf(tot), 1e-12f);
    Cb[(size_t)b * DD + t]       = f2bf(v0 * inv);
    Cb[(size_t)b * DD + t + 256] = f2bf(v1 * inv);
  } else {
    int i = (b - KC) * 2048 + t * 8;            // 32 blocks cover 65536 elems
    const float4* src = (const float4*)(conv_w + i);
    float4 a = src[0], c = src[1];
    upk4 w0, w1;
    w0[0] = f2bf(a.x); w0[1] = f2bf(a.y); w0[2] = f2bf(a.z); w0[3] = f2bf(a.w);
    w1[0] = f2bf(c.x); w1[1] = f2bf(c.y); w1[2] = f2bf(c.z); w1[3] = f2bf(c.w);
    *(upk4*)(Wb + i)     = w0;
    *(upk4*)(Wb + i + 4) = w1;
  }
}

// ---------- fused xnorm + projection ----------
// Per block: 128 l-positions. Load x[n, 0:128, l0:l0+128] fp32, transpose+norm
// to bf16 Xn(l,c) in LDS, GEMM against Wb(D,C) in 4 d-chunks -> fT(N,L,D) bf16.
// LDS: xt (c,l) bf16 swizzled 32K | Xn (l,c) bf16 swizzled 32K ; Ws aliases xt.
__global__ __launch_bounds__(512) void k_xproj(const float* __restrict__ x,
                                               const unsigned short* __restrict__ Wb,
                                               const float* __restrict__ conv_b,
                                               unsigned short* __restrict__ fT) {
  __shared__ __align__(16) char smem[65536];
  char* xt = smem;                      // swizzled (c,l): byte = c*256 + ((l*2)^((c&7)<<4))
  char* Xn = smem + 32768;              // swizzled (l,c): byte = l*256 + ((c*2)^((l&7)<<4))
  float* psum = (float*)(smem + 32768); // [4][128], aliases Xn (dead before Xn writes)
  char* Ws = smem;                      // aliases xt (dead after P3)
  int n = blockIdx.y, l0 = blockIdx.x * 128;
  int t = threadIdx.x, lane = t & 63, wid = t >> 6;

  // P1: load x rows (c, 512B each) -> bf16 -> xt swizzled
  {
    int c = t >> 2;
    const float* xrow = x + ((size_t)n * CD + c) * HW + l0;
    #pragma unroll
    for (int j = 0; j < 8; j++) {
      int fq = (t & 3) + 4 * j;                 // float4 slot; l = fq*4
      float4 v = *(const float4*)(xrow + fq * 4);
      upk4 w;
      w[0] = f2bf(v.x); w[1] = f2bf(v.y); w[2] = f2bf(v.z); w[3] = f2bf(v.w);
      *(upk4*)(xt + c * 256 + ((fq * 8) ^ ((c & 7) << 4))) = w;
    }
  }
  __syncthreads();
  // P2: per-l sum of squares (partials over 4 c-ranges)
  {
    int l = t & 127, ch = t >> 7;
    float ss = 0.f;
    #pragma unroll
    for (int i = 0; i < 32; i++) {
      int c = ch * 32 + i;
      float v = bf2f(*(const unsigned short*)(xt + c * 256 + (((l * 2)) ^ ((c & 7) << 4))));
      ss += v * v;
    }
    psum[ch * 128 + l] = ss;
  }
  __syncthreads();
  // P3a: each thread computes inv for its l; P3b: write Xn (l,c) swizzled
  {
    int l = t >> 2, cb = (t & 3) * 32;
    float tot = psum[l] + psum[128 + l] + psum[256 + l] + psum[384 + l];
    float inv = 1.0f / fmaxf(sqrtf(tot), 1e-12f);
    __syncthreads();                            // psum reads done before Xn writes
    #pragma unroll
    for (int g = 0; g < 4; g++) {
      int cc = cb + g * 8;
      upk8 w;
      #pragma unroll
      for (int i = 0; i < 8; i++) {
        int c = cc + i;
        float v = bf2f(*(const unsigned short*)(xt + c * 256 + (((l * 2)) ^ ((c & 7) << 4))));
        w[i] = f2bf(v * inv);
      }
      *(upk8*)(Xn + l * 256 + ((cc * 2) ^ ((l & 7) << 4))) = w;
    }
  }

  // P4: GEMM, 4 d-chunks of 128. 8 waves 2x4: wave tile 64(l) x 32(d).
  int wr = wid >> 2, wc = wid & 3;
  for (int dch = 0; dch < 4; dch++) {
    __syncthreads();                            // Xn ready / prev chunk reads done
    {
      int d = t >> 2;
      const unsigned short* wrow = Wb + (size_t)(dch * 128 + d) * CD;
      #pragma unroll
      for (int j = 0; j < 4; j++) {
        int ch16 = (t & 3) + 4 * j;             // 16B chunk; c0 = ch16*8
        bfrag v = *(const bfrag*)(wrow + ch16 * 8);
        *(bfrag*)(Ws + d * 256 + ((ch16 * 16) ^ ((d & 7) << 4))) = v;
      }
    }
    __syncthreads();
    facc acc[4][2];
    facc zero = {0.f, 0.f, 0.f, 0.f};
    #pragma unroll
    for (int m = 0; m < 4; m++) { acc[m][0] = zero; acc[m][1] = zero; }
    #pragma unroll
    for (int kk = 0; kk < 128; kk += 32) {
      int c0 = kk + ((lane >> 4) << 3);
      bfrag af[4], bf[2];
      #pragma unroll
      for (int m = 0; m < 4; m++) {
        int row = wr * 64 + m * 16 + (lane & 15);
        af[m] = *(const bfrag*)(Xn + row * 256 + ((c0 * 2) ^ ((row & 7) << 4)));
      }
      #pragma unroll
      for (int j = 0; j < 2; j++) {
        int drow = wc * 32 + j * 16 + (lane & 15);
        bf[j] = *(const bfrag*)(Ws + drow * 256 + ((c0 * 2) ^ ((drow & 7) << 4)));
      }
      #pragma unroll
      for (int m = 0; m < 4; m++)
        #pragma unroll
        for (int j = 0; j < 2; j++)
          acc[m][j] = __builtin_amdgcn_mfma_f32_16x16x32_bf16(af[m], bf[j], acc[m][j], 0, 0, 0);
    }
    // epilogue: fT[n, l0+row, dch*128+col] bf16 (+bias)
    int r0 = (lane >> 4) << 2, cl = lane & 15;
    #pragma unroll
    for (int m = 0; m < 4; m++) {
      int grow = wr * 64 + m * 16 + r0;
      #pragma unroll
      for (int j = 0; j < 2; j++) {
        int gcol = dch * 128 + wc * 32 + j * 16 + cl;
        float bv = conv_b[gcol];
        #pragma unroll
        for (int q = 0; q < 4; q++)
          fT[((size_t)n * HW + l0 + grow + q) * DD + gcol] = f2bf(acc[m][j][q] + bv);
      }
    }
  }
}

// ---------- BT-form bf16 MFMA GEMM (logits only), global_load_lds staging ----------
template<int BM, int BN, int BK, int KLEN, int LDA, int LDB, int LDC,
         int SA, int SB, int SC, int NTM, int NTN>
__global__ __launch_bounds__(256) void gemm_bt(const unsigned short* __restrict__ A,
                                               const unsigned short* __restrict__ B,
                                               float* __restrict__ Cout) {
  constexpr int WM = BM / 2, WN = BN / 2;
  constexpr int FM = WM / 16, FN = WN / 16;
  constexpr int ISS_A = (BM * BK) / 2048;
  constexpr int ISS_B = (BN * BK) / 2048;
  __shared__ __align__(16) unsigned short As[BM][BK];
  __shared__ __align__(16) unsigned short Bs[BN][BK];
  int t = threadIdx.x, lane = t & 63, wid = t >> 6;
  int wr = wid >> 1, wc = wid & 1;
  int bx = blockIdx.x;
  int tn = bx % NTN; bx /= NTN;
  int tm = bx % NTM;
  int n = blockIdx.y;
  const unsigned short* Ab = A + (size_t)n * SA + (size_t)tm * BM * LDA;
  const unsigned short* Bb = B + (size_t)n * SB + (size_t)tn * BN * LDB;
  facc acc[FM][FN];
  facc zero = {0.f, 0.f, 0.f, 0.f};
  #pragma unroll
  for (int m = 0; m < FM; m++)
    #pragma unroll
    for (int j = 0; j < FN; j++) acc[m][j] = zero;

  for (int kt = 0; kt < KLEN; kt += BK) {
    #pragma unroll
    for (int q = 0; q < ISS_A; q++) {
      int chunk = (q * 4 + wid) * 64 + lane;
      int r = chunk >> 3, c8 = (chunk & 7) << 3;
      gll16(Ab + (size_t)r * LDA + kt + c8, (char*)As + (q * 4 + wid) * 1024);
    }
    #pragma unroll
    for (int q = 0; q < ISS_B; q++) {
      int chunk = (q * 4 + wid) * 64 + lane;
      int r = chunk >> 3, c8 = (chunk & 7) << 3;
      gll16(Bb + (size_t)r * LDB + kt + c8, (char*)Bs + (q * 4 + wid) * 1024);
    }
    __syncthreads();
    #pragma unroll
    for (int kk = 0; kk < BK; kk += 32) {
      int krow = kk + ((lane >> 4) << 3);
      bfrag af[FM], bf[FN];
      #pragma unroll
      for (int m = 0; m < FM; m++)
        af[m] = *(const bfrag*)&As[wr * WM + m * 16 + (lane & 15)][krow];
      #pragma unroll
      for (int j = 0; j < FN; j++)
        bf[j] = *(const bfrag*)&Bs[wc * WN + j * 16 + (lane & 15)][krow];
      #pragma unroll
      for (int m = 0; m < FM; m++)
        #pragma unroll
        for (int j = 0; j < FN; j++)
          acc[m][j] = __builtin_amdgcn_mfma_f32_16x16x32_bf16(af[m], bf[j], acc[m][j], 0, 0, 0);
    }
    __syncthreads();
  }

  int r0 = (lane >> 4) << 2, cl = lane & 15;
  #pragma unroll
  for (int m = 0; m < FM; m++) {
    int grow = tm * BM + wr * WM + m * 16 + r0;
    #pragma unroll
    for (int j = 0; j < FN; j++) {
      int gcol = tn * BN + wc * WN + j * 16 + cl;
      #pragma unroll
      for (int q = 0; q < 4; q++)
        Cout[(size_t)n * SC + (size_t)(grow + q) * LDC + gcol] = acc[m][j][q];
    }
  }
}

// ---------- softmax over L=4096 per (n,k) row; fp32 in, bf16 out ----------
__global__ __launch_bounds__(256) void k_softmax(const float* __restrict__ logits,
                                                 unsigned short* __restrict__ s) {
  int row = blockIdx.x;
  const float4* in = (const float4*)(logits + (size_t)row * HW);
  int t = threadIdx.x, wid = t >> 6;
  float4 v[4];
  float mx = -3.4e38f;
  #pragma unroll
  for (int j = 0; j < 4; j++) {
    v[j] = in[j * 256 + t];
    mx = fmaxf(mx, fmaxf(fmaxf(v[j].x, v[j].y), fmaxf(v[j].z, v[j].w)));
  }
  #pragma unroll
  for (int off = 32; off; off >>= 1) mx = fmaxf(mx, __shfl_xor(mx, off));
  __shared__ float redm[4], reds[4];
  if ((t & 63) == 0) redm[wid] = mx;
  __syncthreads();
  mx = fmaxf(fmaxf(redm[0], redm[1]), fmaxf(redm[2], redm[3]));
  float e[4][4];
  float sum = 0.f;
  #pragma unroll
  for (int j = 0; j < 4; j++) {
    e[j][0] = __expf(v[j].x - mx); e[j][1] = __expf(v[j].y - mx);
    e[j][2] = __expf(v[j].z - mx); e[j][3] = __expf(v[j].w - mx);
    sum += e[j][0] + e[j][1] + e[j][2] + e[j][3];
  }
  #pragma unroll
  for (int off = 32; off; off >>= 1) sum += __shfl_xor(sum, off);
  if ((t & 63) == 0) reds[wid] = sum;
  __syncthreads();
  sum = reds[0] + reds[1] + reds[2] + reds[3];
  float rinv = 1.0f / sum;
  upk4* o = (upk4*)(s + (size_t)row * HW);
  #pragma unroll
  for (int j = 0; j < 4; j++) {
    upk4 w;
    w[0] = f2bf(e[j][0] * rinv); w[1] = f2bf(e[j][1] * rinv);
    w[2] = f2bf(e[j][2] * rinv); w[3] = f2bf(e[j][3] * rinv);
    o[j * 256 + t] = w;
  }
}

// ---------- vlad: part[sk,n,k,d] = sum_l s[n,k,l] f[n,l,d], LDS-transposed B ----------
// Grid: (4 d-tiles x 4 sk, NB). Block 256 = 4 waves (2x2), wave tile 32k x 64d.
__global__ __launch_bounds__(256) void k_vlad(const unsigned short* __restrict__ sm,
                                              const unsigned short* __restrict__ fT,
                                              float* __restrict__ part) {
  __shared__ __align__(16) char smem[24576];
  char* As = smem;            // [64k][64l] swz: byte = k*128 + ((l*2)^((k&7)<<4))
  char* Bs = smem + 8192;     // [128d][64l] swz: byte = d*128 + ((l*2)^(((d&7)^((d>>3)&7))<<4))
  int t = threadIdx.x, lane = t & 63, wid = t >> 6;
  int wr = wid >> 1, wc = wid & 1;
  int dt = blockIdx.x & 3, sk = blockIdx.x >> 2, n = blockIdx.y;
  int dbase = dt * 128;
  facc acc[2][4];
  facc zero = {0.f, 0.f, 0.f, 0.f};
  #pragma unroll
  for (int m = 0; m < 2; m++)
    #pragma unroll
    for (int j = 0; j < 4; j++) acc[m][j] = zero;

  for (int ks = 0; ks < 16; ks++) {
    int l0 = sk * 1024 + ks * 64;
    // stage A (s-tile 64k x 64l), swizzled
    #pragma unroll
    for (int q = 0; q < 2; q++) {
      int ch = q * 256 + t;                      // k = ch>>3, lc = ch&7
      int k = ch >> 3, lc = ch & 7;
      bfrag v = *(const bfrag*)(sm + ((size_t)n * KC + k) * HW + l0 + lc * 8);
      *(bfrag*)(As + k * 128 + ((lc * 16) ^ ((k & 7) << 4))) = v;
    }
    // stage B transposed (fT rows l -> Bs[d][l]), swizzled scalar writes
    #pragma unroll
    for (int q = 0; q < 4; q++) {
      int ch = q * 256 + t;                      // l = ch>>4, dc = ch&15
      int l = ch >> 4, dc = ch & 15;
      bfrag v = *(const bfrag*)(fT + ((size_t)n * HW + l0 + l) * DD + dbase + dc * 8);
      #pragma unroll
      for (int i = 0; i < 8; i++) {
        int d = dc * 8 + i;
        int swz = (((d & 7) ^ ((d >> 3) & 7)) << 4);
        *(unsigned short*)(Bs + d * 128 + ((l * 2) ^ swz)) = (unsigned short)v[i];
      }
    }
    __syncthreads();
    #pragma unroll
    for (int kk = 0; kk < 64; kk += 32) {
      int lk = kk + ((lane >> 4) << 3);
      bfrag af[2], bf[4];
      #pragma unroll
      for (int m = 0; m < 2; m++) {
        int krow = wr * 32 + m * 16 + (lane & 15);
        af[m] = *(const bfrag*)(As + krow * 128 + ((lk * 2) ^ ((krow & 7) << 4)));
      }
      #pragma unroll
      for (int j = 0; j < 4; j++) {
        int d = wc * 64 + j * 16 + (lane & 15);
        int swz = (((d & 7) ^ ((d >> 3) & 7)) << 4);
        bf[j] = *(const bfrag*)(Bs + d * 128 + ((lk * 2) ^ swz));
      }
      #pragma unroll
      for (int m = 0; m < 2; m++)
        #pragma unroll
        for (int j = 0; j < 4; j++)
          acc[m][j] = __builtin_amdgcn_mfma_f32_16x16x32_bf16(af[m], bf[j], acc[m][j], 0, 0, 0);
    }
    __syncthreads();
  }
  int r0 = (lane >> 4) << 2, cl = lane & 15;
  size_t base = ((size_t)(sk * NB + n)) * (KC * DD);
  #pragma unroll
  for (int m = 0; m < 2; m++) {
    int krow = wr * 32 + m * 16 + r0;
    #pragma unroll
    for (int j = 0; j < 4; j++) {
      int d = dbase + wc * 64 + j * 16 + cl;
      #pragma unroll
      for (int q = 0; q < 4; q++)
        part[base + (size_t)(krow + q) * DD + d] = acc[m][j][q];
    }
  }
}

// ---------- reduce split-K partials (4) ----------
__global__ __launch_bounds__(256) void k_reduce(const float* __restrict__ part,
                                                float* __restrict__ out) {
  int i = blockIdx.x * 256 + threadIdx.x;
  float s = 0.f;
  #pragma unroll
  for (int skk = 0; skk < 4; skk++) s += part[(size_t)skk * (NB * KC * DD) + i];
  out[i] = s;
}

extern "C" void kernel_launch(void* const* d_in, const int* in_sizes, int n_in,
                              void* d_out, int out_size, void* d_ws, size_t ws_size,
                              hipStream_t stream) {
  const float* x         = (const float*)d_in[0];
  const float* conv_w    = (const float*)d_in[1];
  const float* conv_b    = (const float*)d_in[2];
  const float* centroids = (const float*)d_in[3];
  float* out = (float*)d_out;
  char* ws = (char*)d_ws;

  // ws layout (bytes):
  //   Wb   @ 0          (128 KB)   conv_w bf16 (D,C)
  //   Cb   @ 131072     (64 KB)    normalized centroids bf16 (K,D)
  //   fT   @ 196608     (64 MB)    f bf16 (N,L,D)
  //   lg   @ 67305472   (16 MB)    logits fp32 (N,K,L)
  //   sm   @ 84082688   (8 MB)     softmax bf16 (N,K,L)
  //   part @ 92471296   (8 MB)     vlad partials fp32 (4,N,K,D)
  unsigned short* Wb  = (unsigned short*)(ws);
  unsigned short* Cb  = (unsigned short*)(ws + 131072);
  unsigned short* fT  = (unsigned short*)(ws + 196608);
  float*          lg  = (float*)(ws + 67305472ull);
  unsigned short* sm  = (unsigned short*)(ws + 84082688ull);
  float*          part= (float*)(ws + 92471296ull);

  k_prep<<<dim3(96), dim3(256), 0, stream>>>(conv_w, centroids, Wb, Cb);

  // fused xnorm + projection -> fT(N,L,D)
  k_xproj<<<dim3(32, NB), dim3(512), 0, stream>>>(x, Wb, conv_b, fT);

  // logits(K,L) = Cb(K,D) * fT(L,D)^T
  gemm_bt<64, 128, 64, 512, DD, DD, HW, 0, HW * DD, KC * HW, 1, 32>
      <<<dim3(32, NB), dim3(256), 0, stream>>>(Cb, fT, lg);

  k_softmax<<<dim3(NB * KC), dim3(256), 0, stream>>>(lg, sm);

  // vlad partials: s(K,L) * f(L,D), split-L into 4 chunks of 1024
  k_vlad<<<dim3(16, NB), dim3(256), 0, stream>>>(sm, fT, part);

  k_reduce<<<dim3(NB * KC * DD / 256), dim3(256), 0, stream>>>(part, out);

  (void)in_sizes; (void)n_in; (void)out_size; (void)ws_size;
}

// Round 4
// 75.222 us; speedup vs baseline: 1.8354x; 1.0558x over previous
//
#include <hip/hip_runtime.h>

#define NB 16     // batch
#define CD 128    // channels
#define HW 4096   // spatial L
#define DD 512    // projected dim
#define KC 64     // clusters

typedef __attribute__((ext_vector_type(8))) short bfrag;           // 8 bf16 (4 VGPR)
typedef __attribute__((ext_vector_type(8))) unsigned short upk8;   // 8 bf16
typedef __attribute__((ext_vector_type(4))) float facc;            // MFMA acc
typedef __attribute__((ext_vector_type(4))) unsigned short upk4;   // 4 bf16

__device__ __forceinline__ unsigned short f2bf(float f) {
  union { float f; unsigned u; } v; v.f = f;
  unsigned r = v.u + 0x7fffu + ((v.u >> 16) & 1u);   // RNE
  return (unsigned short)(r >> 16);
}
__device__ __forceinline__ float bf2f(unsigned short h) {
  union { unsigned u; float f; } v; v.u = ((unsigned)h) << 16; return v.f;
}

// async global->LDS, 16B per lane (LDS dest = wave-uniform base + lane*16)
__device__ __forceinline__ void gll16(const void* g, void* l) {
  __builtin_amdgcn_global_load_lds(
      (__attribute__((address_space(1))) void*)(uintptr_t)g,
      (__attribute__((address_space(3))) void*)(uintptr_t)l, 16, 0, 0);
}

// ---------- prep: centroid L2-normalize -> bf16 ; conv_w -> bf16 ----------
__global__ __launch_bounds__(256) void k_prep(const float* __restrict__ conv_w,
                                              const float* __restrict__ centroids,
                                              unsigned short* __restrict__ Wb,
                                              unsigned short* __restrict__ Cb) {
  int b = blockIdx.x, t = threadIdx.x;
  if (b < KC) {
    const float* row = centroids + (size_t)b * DD;
    float v0 = row[t], v1 = row[t + 256];
    float ss = v0 * v0 + v1 * v1;
    #pragma unroll
    for (int off = 32; off; off >>= 1) ss += __shfl_xor(ss, off);
    __shared__ float red[4];
    if ((t & 63) == 0) red[t >> 6] = ss;
    __syncthreads();
    float tot = red[0] + red[1] + red[2] + red[3];
    float inv = 1.0f / fmaxf(sqrtf(tot), 1e-12f);
    Cb[(size_t)b * DD + t]       = f2bf(v0 * inv);
    Cb[(size_t)b * DD + t + 256] = f2bf(v1 * inv);
  } else {
    int i = (b - KC) * 2048 + t * 8;            // 32 blocks cover 65536 elems
    const float4* src = (const float4*)(conv_w + i);
    float4 a = src[0], c = src[1];
    upk4 w0, w1;
    w0[0] = f2bf(a.x); w0[1] = f2bf(a.y); w0[2] = f2bf(a.z); w0[3] = f2bf(a.w);
    w1[0] = f2bf(c.x); w1[1] = f2bf(c.y); w1[2] = f2bf(c.z); w1[3] = f2bf(c.w);
    *(upk4*)(Wb + i)     = w0;
    *(upk4*)(Wb + i + 4) = w1;
  }
}

// ---------- fused xnorm + projection -> fT(N,L,D) bf16 ----------
__global__ __launch_bounds__(512) void k_xproj(const float* __restrict__ x,
                                               const unsigned short* __restrict__ Wb,
                                               const float* __restrict__ conv_b,
                                               unsigned short* __restrict__ fT) {
  __shared__ __align__(16) char smem[65536];
  char* xt = smem;                      // swizzled (c,l): byte = c*256 + ((l*2)^((c&7)<<4))
  char* Xn = smem + 32768;              // swizzled (l,c): byte = l*256 + ((c*2)^((l&7)<<4))
  float* psum = (float*)(smem + 32768); // [4][128], aliases Xn (dead before Xn writes)
  char* Ws = smem;                      // aliases xt (dead after P3)
  int n = blockIdx.y, l0 = blockIdx.x * 128;
  int t = threadIdx.x, lane = t & 63, wid = t >> 6;

  // P1: load x rows (c, 512B each) -> bf16 -> xt swizzled
  {
    int c = t >> 2;
    const float* xrow = x + ((size_t)n * CD + c) * HW + l0;
    #pragma unroll
    for (int j = 0; j < 8; j++) {
      int fq = (t & 3) + 4 * j;                 // float4 slot; l = fq*4
      float4 v = *(const float4*)(xrow + fq * 4);
      upk4 w;
      w[0] = f2bf(v.x); w[1] = f2bf(v.y); w[2] = f2bf(v.z); w[3] = f2bf(v.w);
      *(upk4*)(xt + c * 256 + ((fq * 8) ^ ((c & 7) << 4))) = w;
    }
  }
  __syncthreads();
  // P2: per-l sum of squares (partials over 4 c-ranges)
  {
    int l = t & 127, ch = t >> 7;
    float ss = 0.f;
    #pragma unroll
    for (int i = 0; i < 32; i++) {
      int c = ch * 32 + i;
      float v = bf2f(*(const unsigned short*)(xt + c * 256 + (((l * 2)) ^ ((c & 7) << 4))));
      ss += v * v;
    }
    psum[ch * 128 + l] = ss;
  }
  __syncthreads();
  // P3: inv per l; write Xn (l,c) swizzled
  {
    int l = t >> 2, cb = (t & 3) * 32;
    float tot = psum[l] + psum[128 + l] + psum[256 + l] + psum[384 + l];
    float inv = 1.0f / fmaxf(sqrtf(tot), 1e-12f);
    __syncthreads();                            // psum reads done before Xn writes
    #pragma unroll
    for (int g = 0; g < 4; g++) {
      int cc = cb + g * 8;
      upk8 w;
      #pragma unroll
      for (int i = 0; i < 8; i++) {
        int c = cc + i;
        float v = bf2f(*(const unsigned short*)(xt + c * 256 + (((l * 2)) ^ ((c & 7) << 4))));
        w[i] = f2bf(v * inv);
      }
      *(upk8*)(Xn + l * 256 + ((cc * 2) ^ ((l & 7) << 4))) = w;
    }
  }

  // P4: GEMM, 4 d-chunks of 128. 8 waves 2x4: wave tile 64(l) x 32(d).
  int wr = wid >> 2, wc = wid & 3;
  for (int dch = 0; dch < 4; dch++) {
    __syncthreads();
    {
      int d = t >> 2;
      const unsigned short* wrow = Wb + (size_t)(dch * 128 + d) * CD;
      #pragma unroll
      for (int j = 0; j < 4; j++) {
        int ch16 = (t & 3) + 4 * j;             // 16B chunk; c0 = ch16*8
        bfrag v = *(const bfrag*)(wrow + ch16 * 8);
        *(bfrag*)(Ws + d * 256 + ((ch16 * 16) ^ ((d & 7) << 4))) = v;
      }
    }
    __syncthreads();
    facc acc[4][2];
    facc zero = {0.f, 0.f, 0.f, 0.f};
    #pragma unroll
    for (int m = 0; m < 4; m++) { acc[m][0] = zero; acc[m][1] = zero; }
    #pragma unroll
    for (int kk = 0; kk < 128; kk += 32) {
      int c0 = kk + ((lane >> 4) << 3);
      bfrag af[4], bf[2];
      #pragma unroll
      for (int m = 0; m < 4; m++) {
        int row = wr * 64 + m * 16 + (lane & 15);
        af[m] = *(const bfrag*)(Xn + row * 256 + ((c0 * 2) ^ ((row & 7) << 4)));
      }
      #pragma unroll
      for (int j = 0; j < 2; j++) {
        int drow = wc * 32 + j * 16 + (lane & 15);
        bf[j] = *(const bfrag*)(Ws + drow * 256 + ((c0 * 2) ^ ((drow & 7) << 4)));
      }
      #pragma unroll
      for (int m = 0; m < 4; m++)
        #pragma unroll
        for (int j = 0; j < 2; j++)
          acc[m][j] = __builtin_amdgcn_mfma_f32_16x16x32_bf16(af[m], bf[j], acc[m][j], 0, 0, 0);
    }
    int r0 = (lane >> 4) << 2, cl = lane & 15;
    #pragma unroll
    for (int m = 0; m < 4; m++) {
      int grow = wr * 64 + m * 16 + r0;
      #pragma unroll
      for (int j = 0; j < 2; j++) {
        int gcol = dch * 128 + wc * 32 + j * 16 + cl;
        float bv = conv_b[gcol];
        #pragma unroll
        for (int q = 0; q < 4; q++)
          fT[((size_t)n * HW + l0 + grow + q) * DD + gcol] = f2bf(acc[m][j][q] + bv);
      }
    }
  }
}

// ---------- logits GEMM + exp epilogue + per-block row sums ----------
// e[n,k,l] = exp(Cb[k,:] . fT[n,l,:]) bf16 ; psums[n][tn][k] = sum_l(tile) e
// Logits bounded (|c|=1, |f row| <~ 3.5) -> exp without max subtraction is safe.
__global__ __launch_bounds__(256) void k_logits(const unsigned short* __restrict__ Cb,
                                                const unsigned short* __restrict__ fT,
                                                unsigned short* __restrict__ e,
                                                float* __restrict__ psums) {
  __shared__ __align__(16) unsigned short As[KC][64];     // Cb tile (k, d-chunk)
  __shared__ __align__(16) unsigned short Bs[128][64];    // fT tile (l, d-chunk)
  __shared__ float ps[64][2];
  int t = threadIdx.x, lane = t & 63, wid = t >> 6;
  int wr = wid >> 1, wc = wid & 1;
  int tn = blockIdx.x, n = blockIdx.y;
  const unsigned short* Bb = fT + (size_t)n * HW * DD + (size_t)tn * 128 * DD;
  facc acc[2][4];
  facc zero = {0.f, 0.f, 0.f, 0.f};
  #pragma unroll
  for (int m = 0; m < 2; m++)
    #pragma unroll
    for (int j = 0; j < 4; j++) acc[m][j] = zero;

  for (int kt = 0; kt < DD; kt += 64) {
    #pragma unroll
    for (int q = 0; q < 2; q++) {               // A: 64x64
      int chunk = (q * 4 + wid) * 64 + lane;
      int r = chunk >> 3, c8 = (chunk & 7) << 3;
      gll16(Cb + (size_t)r * DD + kt + c8, (char*)As + (q * 4 + wid) * 1024);
    }
    #pragma unroll
    for (int q = 0; q < 4; q++) {               // B: 128x64
      int chunk = (q * 4 + wid) * 64 + lane;
      int r = chunk >> 3, c8 = (chunk & 7) << 3;
      gll16(Bb + (size_t)r * DD + kt + c8, (char*)Bs + (q * 4 + wid) * 1024);
    }
    __syncthreads();
    #pragma unroll
    for (int kk = 0; kk < 64; kk += 32) {
      int krow = kk + ((lane >> 4) << 3);
      bfrag af[2], bf[4];
      #pragma unroll
      for (int m = 0; m < 2; m++)
        af[m] = *(const bfrag*)&As[wr * 32 + m * 16 + (lane & 15)][krow];
      #pragma unroll
      for (int j = 0; j < 4; j++)
        bf[j] = *(const bfrag*)&Bs[wc * 64 + j * 16 + (lane & 15)][krow];
      #pragma unroll
      for (int m = 0; m < 2; m++)
        #pragma unroll
        for (int j = 0; j < 4; j++)
          acc[m][j] = __builtin_amdgcn_mfma_f32_16x16x32_bf16(af[m], bf[j], acc[m][j], 0, 0, 0);
    }
    __syncthreads();
  }

  int r0 = (lane >> 4) << 2, cl = lane & 15;
  float rs[2][4] = {{0.f,0.f,0.f,0.f},{0.f,0.f,0.f,0.f}};
  #pragma unroll
  for (int m = 0; m < 2; m++) {
    int grow = wr * 32 + m * 16 + r0;
    #pragma unroll
    for (int j = 0; j < 4; j++) {
      int gcol = tn * 128 + wc * 64 + j * 16 + cl;
      #pragma unroll
      for (int q = 0; q < 4; q++) {
        float ev = __expf(acc[m][j][q]);
        e[((size_t)n * KC + grow + q) * HW + gcol] = f2bf(ev);
        rs[m][q] += ev;
      }
    }
  }
  #pragma unroll
  for (int m = 0; m < 2; m++)
    #pragma unroll
    for (int q = 0; q < 4; q++) {
      float v = rs[m][q];
      v += __shfl_xor(v, 1); v += __shfl_xor(v, 2);
      v += __shfl_xor(v, 4); v += __shfl_xor(v, 8);
      if (cl == 0) ps[wr * 32 + m * 16 + r0 + q][wc] = v;
    }
  __syncthreads();
  if (t < 64) psums[((size_t)n * 32 + tn) * 64 + t] = ps[t][0] + ps[t][1];
}

// ---------- rinv[n,k] = 1 / sum_tn psums ----------
__global__ __launch_bounds__(256) void k_rinv(const float* __restrict__ psums,
                                              float* __restrict__ rinv) {
  int i = blockIdx.x * 256 + threadIdx.x;       // 1024 total
  int n = i >> 6, k = i & 63;
  float s = 0.f;
  #pragma unroll
  for (int tn = 0; tn < 32; tn++) s += psums[((size_t)n * 32 + tn) * 64 + k];
  rinv[i] = 1.0f / s;
}

// ---------- vlad partials: part[sk,n,k,d] = sum_l e[n,k,l] f[n,l,d] ----------
// Grid: (4 d-tiles x 4 sk, NB). Block 256 = 4 waves (2x2). BK=128 l per stage.
__global__ __launch_bounds__(256) void k_vlad(const unsigned short* __restrict__ e,
                                              const unsigned short* __restrict__ fT,
                                              float* __restrict__ part) {
  __shared__ __align__(16) char smem[49152];
  char* As = smem;            // [64k][128l]: byte = k*256 + ((l*2)^((k&7)<<4))
  char* Bs = smem + 16384;    // [128d][128l]: byte = d*256 + ((l*2)^(((d&7)^((d>>3)&7))<<4))
  int t = threadIdx.x, lane = t & 63, wid = t >> 6;
  int wr = wid >> 1, wc = wid & 1;
  int dt = blockIdx.x & 3, sk = blockIdx.x >> 2, n = blockIdx.y;
  int dbase = dt * 128;
  facc acc[2][4];
  facc zero = {0.f, 0.f, 0.f, 0.f};
  #pragma unroll
  for (int m = 0; m < 2; m++)
    #pragma unroll
    for (int j = 0; j < 4; j++) acc[m][j] = zero;

  for (int ks = 0; ks < 8; ks++) {
    int l0 = sk * 1024 + ks * 128;
    // stage A (e-tile 64k x 128l), swizzled b128 writes
    #pragma unroll
    for (int q = 0; q < 4; q++) {
      int ch = q * 256 + t;                      // k = ch>>4, lc = ch&15
      int k = ch >> 4, lc = ch & 15;
      bfrag v = *(const bfrag*)(e + ((size_t)n * KC + k) * HW + l0 + lc * 8);
      *(bfrag*)(As + k * 256 + ((lc * 16) ^ ((k & 7) << 4))) = v;
    }
    // stage B transposed (fT rows l -> Bs[d][l]), swizzled scalar writes
    #pragma unroll
    for (int q = 0; q < 8; q++) {
      int ch = q * 256 + t;                      // l = ch>>4, dc = ch&15
      int l = ch >> 4, dc = ch & 15;
      bfrag v = *(const bfrag*)(fT + ((size_t)n * HW + l0 + l) * DD + dbase + dc * 8);
      #pragma unroll
      for (int i = 0; i < 8; i++) {
        int d = dc * 8 + i;
        int swz = (((d & 7) ^ ((d >> 3) & 7)) << 4);
        *(unsigned short*)(Bs + d * 256 + ((l * 2) ^ swz)) = (unsigned short)v[i];
      }
    }
    __syncthreads();
    #pragma unroll
    for (int kk = 0; kk < 128; kk += 32) {
      int lk = kk + ((lane >> 4) << 3);
      bfrag af[2], bf[4];
      #pragma unroll
      for (int m = 0; m < 2; m++) {
        int krow = wr * 32 + m * 16 + (lane & 15);
        af[m] = *(const bfrag*)(As + krow * 256 + ((lk * 2) ^ ((krow & 7) << 4)));
      }
      #pragma unroll
      for (int j = 0; j < 4; j++) {
        int d = wc * 64 + j * 16 + (lane & 15);
        int swz = (((d & 7) ^ ((d >> 3) & 7)) << 4);
        bf[j] = *(const bfrag*)(Bs + d * 256 + ((lk * 2) ^ swz));
      }
      #pragma unroll
      for (int m = 0; m < 2; m++)
        #pragma unroll
        for (int j = 0; j < 4; j++)
          acc[m][j] = __builtin_amdgcn_mfma_f32_16x16x32_bf16(af[m], bf[j], acc[m][j], 0, 0, 0);
    }
    __syncthreads();
  }
  int r0 = (lane >> 4) << 2, cl = lane & 15;
  size_t base = ((size_t)(sk * NB + n)) * (KC * DD);
  #pragma unroll
  for (int m = 0; m < 2; m++) {
    int krow = wr * 32 + m * 16 + r0;
    #pragma unroll
    for (int j = 0; j < 4; j++) {
      int d = dbase + wc * 64 + j * 16 + cl;
      #pragma unroll
      for (int q = 0; q < 4; q++)
        part[base + (size_t)(krow + q) * DD + d] = acc[m][j][q];
    }
  }
}

// ---------- reduce split-K partials (4) and normalize by rinv ----------
__global__ __launch_bounds__(256) void k_reduce(const float* __restrict__ part,
                                                const float* __restrict__ rinv,
                                                float* __restrict__ out) {
  int i = blockIdx.x * 256 + threadIdx.x;
  float s = 0.f;
  #pragma unroll
  for (int skk = 0; skk < 4; skk++) s += part[(size_t)skk * (NB * KC * DD) + i];
  out[i] = s * rinv[i >> 9];                    // i>>9 = n*64+k
}

extern "C" void kernel_launch(void* const* d_in, const int* in_sizes, int n_in,
                              void* d_out, int out_size, void* d_ws, size_t ws_size,
                              hipStream_t stream) {
  const float* x         = (const float*)d_in[0];
  const float* conv_w    = (const float*)d_in[1];
  const float* conv_b    = (const float*)d_in[2];
  const float* centroids = (const float*)d_in[3];
  float* out = (float*)d_out;
  char* ws = (char*)d_ws;

  // ws layout (bytes):
  //   Wb    @ 0          (128 KB)   conv_w bf16 (D,C)
  //   Cb    @ 131072     (64 KB)    normalized centroids bf16 (K,D)
  //   fT    @ 196608     (64 MB)    f bf16 (N,L,D)
  //   e     @ 67305472   (8 MB)     exp(logits) bf16 (N,K,L)
  //   psums @ 75694080   (128 KB)   per-tile row sums fp32 (N,32,K)
  //   rinv  @ 75825152   (4 KB)     1/rowsum fp32 (N,K)
  //   part  @ 75829248   (8 MB)     vlad partials fp32 (4,N,K,D)
  unsigned short* Wb   = (unsigned short*)(ws);
  unsigned short* Cb   = (unsigned short*)(ws + 131072);
  unsigned short* fT   = (unsigned short*)(ws + 196608);
  unsigned short* ebuf = (unsigned short*)(ws + 67305472ull);
  float*          psums= (float*)(ws + 75694080ull);
  float*          rinv = (float*)(ws + 75825152ull);
  float*          part = (float*)(ws + 75829248ull);

  k_prep<<<dim3(96), dim3(256), 0, stream>>>(conv_w, centroids, Wb, Cb);

  // fused xnorm + projection -> fT(N,L,D)
  k_xproj<<<dim3(32, NB), dim3(512), 0, stream>>>(x, Wb, conv_b, fT);

  // e(K,L) = exp(Cb(K,D) * fT(L,D)^T), bf16; psums per l-tile
  k_logits<<<dim3(32, NB), dim3(256), 0, stream>>>(Cb, fT, ebuf, psums);

  k_rinv<<<dim3(4), dim3(256), 0, stream>>>(psums, rinv);

  // vlad partials: e(K,L) * f(L,D), split-L into 4 chunks of 1024
  k_vlad<<<dim3(16, NB), dim3(256), 0, stream>>>(ebuf, fT, part);

  k_reduce<<<dim3(NB * KC * DD / 256), dim3(256), 0, stream>>>(part, rinv, out);

  (void)in_sizes; (void)n_in; (void)out_size; (void)ws_size;
}